// Round 4
// baseline (290.503 us; speedup 1.0000x reference)
//
#include <hip/hip_runtime.h>
#include <hip/hip_bf16.h>

typedef unsigned short u16;
typedef unsigned int u32;
typedef __attribute__((ext_vector_type(8))) short bf16x8;
typedef __attribute__((ext_vector_type(4))) float f32x4;

#define T_DIM 2048
#define B_DIM 32
#define H_DIM 512
#define M_DIM (T_DIM * B_DIM)

__device__ inline unsigned pack2(float a, float b) {
  union { __hip_bfloat162 h2; unsigned u; } c;
  c.h2 = __float22bfloat162_rn(make_float2(a, b));
  return c.u;
}

// Async 16B/lane global->LDS copy. LDS side is wave-uniform base + lane*16 (m104).
__device__ inline void gload_lds16(const float* g, float* lds) {
  __builtin_amdgcn_global_load_lds((const __attribute__((address_space(1))) u32*)g,
                                   (__attribute__((address_space(3))) u32*)lds, 16, 0, 0);
}

// Precompute: r[b*512+h] = hidden[b]·W1[h] + b_attn[h]; u[h] = W3[h]·W_cov;
// W2bf = bf16(W2) in FRAGMENT-MAJOR layout: chunk (f= h>>4, ks= k>>5) of 1KB,
// within chunk: lane (quad= (k>>3)&3, c= h&15) * 16B + (k&7)*2B.
__global__ __launch_bounds__(256) void prep_kernel(
    const float* __restrict__ hidden, const float* __restrict__ W_attn,
    const float* __restrict__ b_attn, const float* __restrict__ W_cov,
    u16* __restrict__ W2bf, float* __restrict__ r, float* __restrict__ u)
{
  const int tid = blockIdx.x * 256 + threadIdx.x;  // 0..65535
  const int pair = tid >> 2;                       // b*512 + h
  const int kq = tid & 3;
  const int b = pair >> 9, h = pair & 511;

  {
    const float* hid = hidden + b * 512 + kq * 128;
    const float* w1 = W_attn + (size_t)h * 1536 + kq * 128;
    float acc = 0.f;
    #pragma unroll 8
    for (int k = 0; k < 128; k += 4) {
      float4 x = *(const float4*)(hid + k);
      float4 w = *(const float4*)(w1 + k);
      acc += x.x * w.x + x.y * w.y + x.z * w.z + x.w * w.w;
    }
    acc += __shfl_xor(acc, 1);
    acc += __shfl_xor(acc, 2);
    if (kq == 0) r[pair] = acc + b_attn[h];
  }

  {
    int j0 = tid * 4;
    int hh = j0 >> 9, kk = j0 & 511;
    float4 w = *(const float4*)(W_attn + (size_t)hh * 1536 + 512 + kk);
    uint2 p;
    p.x = pack2(w.x, w.y);
    p.y = pack2(w.z, w.w);
    int f = hh >> 4, c = hh & 15;
    int ks = kk >> 5, quad = (kk >> 3) & 3, e = kk & 7;   // e in {0,4}
    *(uint2*)(W2bf + (size_t)((f * 16 + ks) * 64 + quad * 16 + c) * 8 + e) = p;
  }

  if (tid < 2048) {
    int h3 = tid >> 2;
    const float* w3 = W_attn + (size_t)h3 * 1536 + 1024 + kq * 128;
    const float* wc = W_cov + kq * 128;
    float su = 0.f;
    #pragma unroll 8
    for (int k = 0; k < 128; k += 4) {
      float4 a = *(const float4*)(w3 + k);
      float4 c = *(const float4*)(wc + k);
      su += a.x * c.x + a.y * c.y + a.z * c.z + a.w * c.w;
    }
    su += __shfl_xor(su, 1);
    su += __shfl_xor(su, 2);
    if (kq == 0) u[h3] = su;
  }
}

// One block (512 thr, 8 waves) per 64-row m-tile. A staged as RAW FP32 via async
// global_load_lds in four 32KB K-quarters, double-buffered (2x32KB LDS). Swizzle is
// folded into per-lane GLOBAL addresses (LDS is lane-linear). Each wave owns a
// 64-wide n-slab; B frags are coalesced 1KB loads from fragment-major W2bf, parity
// double-buffered. fp32->bf16 cvt happens at fragment-read time.
__global__ __launch_bounds__(512, 4) void gemm_score(
    const float* __restrict__ enc, const u16* __restrict__ W2bf,
    const float* __restrict__ r, const float* __restrict__ u,
    const float* __restrict__ vv, const float* __restrict__ cov,
    float* __restrict__ part)
{
  const int m0 = blockIdx.x * 64;
  const int tid = threadIdx.x;
  const int lane = tid & 63;
  const int w = tid >> 6;             // wave id 0..7 -> n-slab [w*64, w*64+64)
  const int quad = lane >> 4, col = lane & 15;

  __shared__ float As[2][64 * 128];   // 2 x 32KB: [row][kq-local 128 fp32], 16B-group-swizzled

  // Per-lane constants for async staging: 4 chunks/wave/quarter, chunk c = w*4+it,
  // rows {2c, 2c+1}; lane l covers row 2c+(l>>5), 16B group j=l&31, fetches
  // global group g = j ^ (row&7)  (so LDS slot (row, j) holds data group j^(row&7)).
  const int srow_half = lane >> 5;          // 0/1 within chunk
  const int sj = lane & 31;

  f32x4 acc[4][4] = {};
  const u16* bbase = W2bf + (size_t)w * 32768 + lane * 8;

  // ---- Prologue: issue quarter 0 async, drain, preload B(ks=0) ----
  #pragma unroll
  for (int it = 0; it < 4; ++it) {
    int c = w * 4 + it;
    int row = 2 * c + srow_half;
    int g = sj ^ (row & 7);
    gload_lds16(enc + (size_t)(m0 + row) * 512 + 0 * 128 + g * 4, &As[0][c * 256]);
  }
  __syncthreads();

  bf16x8 bbuf[2][4];
  #pragma unroll
  for (int j = 0; j < 4; ++j)
    bbuf[0][j] = *(const bf16x8*)(bbase + j * 8192);

  // ---- Main loop: 4 quarters x 4 K-steps of 32 ----
  for (int q = 0; q < 4; ++q) {
    // issue next quarter's async loads right after the barrier (they fly under compute)
    if (q < 3) {
      #pragma unroll
      for (int it = 0; it < 4; ++it) {
        int c = w * 4 + it;
        int row = 2 * c + srow_half;
        int g = sj ^ (row & 7);
        gload_lds16(enc + (size_t)(m0 + row) * 512 + (q + 1) * 128 + g * 4,
                    &As[(q + 1) & 1][c * 256]);
      }
    }
    const float* Ab = As[q & 1];
    #pragma unroll
    for (int ksl = 0; ksl < 4; ++ksl) {
      int ksg = q * 4 + ksl;
      if (ksg < 15) {
        #pragma unroll
        for (int j = 0; j < 4; ++j)
          bbuf[(ksg + 1) & 1][j] = *(const bf16x8*)(bbase + j * 8192 + (ksg + 1) * 512);
      }
      const int gb = ksl * 8 + quad * 2;   // first 4-fp32 group of this frag
      #pragma unroll
      for (int i = 0; i < 4; ++i) {
        int row = i * 16 + col;
        int sw = col & 7;                  // row&7 == col&7
        float4 d0 = *(const float4*)&Ab[row * 128 + (gb ^ sw) * 4];
        float4 d1 = *(const float4*)&Ab[row * 128 + ((gb + 1) ^ sw) * 4];
        uint4 pa;
        pa.x = pack2(d0.x, d0.y);
        pa.y = pack2(d0.z, d0.w);
        pa.z = pack2(d1.x, d1.y);
        pa.w = pack2(d1.z, d1.w);
        bf16x8 af = *(bf16x8*)&pa;
        #pragma unroll
        for (int j = 0; j < 4; ++j)
          acc[i][j] = __builtin_amdgcn_mfma_f32_16x16x32_bf16(af, bbuf[ksg & 1][j], acc[i][j], 0, 0, 0);
      }
    }
    if (q < 3) __syncthreads();
  }

  // ---- Epilogue: e = relu(acc + r[b,h] + cov[b,t]*u[h]); partial = e·v over wave's 64 h ----
  float uj[4], vj[4];
  #pragma unroll
  for (int j = 0; j < 4; ++j) {
    int gh = w * 64 + j * 16 + col;
    uj[j] = u[gh];
    vj[j] = vv[gh];
  }
  #pragma unroll
  for (int pr = 0; pr < 2; ++pr) {
    #pragma unroll
    for (int reg = 0; reg < 4; ++reg) {
      int b = pr * 16 + quad * 4 + reg;         // = m & 31 (m0 % 64 == 0)
      const float* rb = r + b * 512;
      float rbj[4];
      #pragma unroll
      for (int j = 0; j < 4; ++j) rbj[j] = rb[w * 64 + j * 16 + col];
      #pragma unroll
      for (int isub = 0; isub < 2; ++isub) {
        int i = pr + isub * 2;
        int t = (m0 >> 5) + isub;
        float cv = cov[b * 2048 + t];
        float s = 0.f;
        #pragma unroll
        for (int j = 0; j < 4; ++j) {
          float e = acc[i][j][reg] + rbj[j] + cv * uj[j];
          e = fmaxf(e, 0.f);
          s += e * vj[j];
        }
        s += __shfl_xor(s, 1);
        s += __shfl_xor(s, 2);
        s += __shfl_xor(s, 4);
        s += __shfl_xor(s, 8);
        if (col == 0) part[(size_t)(w * 32 + b) * 2048 + t] = s;
      }
    }
  }
}

// Softmax over T per batch + coverage update. 32 blocks x 256 threads. part layout [p][b][t].
__global__ __launch_bounds__(256) void softmax_kernel(
    const float* __restrict__ part, const float* __restrict__ cov, float* __restrict__ out)
{
  const int b = blockIdx.x;
  const int tid = threadIdx.x;
  const int lane = tid & 63, wid = tid >> 6;
  __shared__ float red[4];
  float loc[8];
  float lmax = -3.4e38f;
  #pragma unroll
  for (int i = 0; i < 8; ++i) {
    int t = tid + i * 256;
    float s = 0.f;
    #pragma unroll
    for (int p = 0; p < 8; ++p) s += part[(size_t)(p * 32 + b) * 2048 + t];
    loc[i] = s;
    lmax = fmaxf(lmax, s);
  }
  #pragma unroll
  for (int o = 32; o; o >>= 1) lmax = fmaxf(lmax, __shfl_xor(lmax, o));
  if (lane == 0) red[wid] = lmax;
  __syncthreads();
  float bmax = fmaxf(fmaxf(red[0], red[1]), fmaxf(red[2], red[3]));
  __syncthreads();
  float lsum = 0.f;
  #pragma unroll
  for (int i = 0; i < 8; ++i) { loc[i] = __expf(loc[i] - bmax); lsum += loc[i]; }
  #pragma unroll
  for (int o = 32; o; o >>= 1) lsum += __shfl_xor(lsum, o);
  if (lane == 0) red[wid] = lsum;
  __syncthreads();
  float inv = 1.0f / (red[0] + red[1] + red[2] + red[3]);
  #pragma unroll
  for (int i = 0; i < 8; ++i) {
    int t = tid + i * 256;
    float a = loc[i] * inv;
    out[b * 2048 + t] = a;                               // attn_weights [B,1,T]
    out[65536 + b * 2048 + t] = cov[b * 2048 + t] + a;   // coverage_new [B,T]
  }
}

extern "C" void kernel_launch(void* const* d_in, const int* in_sizes, int n_in,
                              void* d_out, int out_size, void* d_ws, size_t ws_size,
                              hipStream_t stream) {
  const float* hidden = (const float*)d_in[0];   // [1,B,H]
  const float* enc    = (const float*)d_in[1];   // [T,B,H]
  const float* cov    = (const float*)d_in[2];   // [B,T]
  const float* W_attn = (const float*)d_in[3];   // [H,3H]
  const float* b_attn = (const float*)d_in[4];   // [H]
  const float* vv     = (const float*)d_in[5];   // [H]
  const float* W_cov  = (const float*)d_in[6];   // [H,1]
  float* out = (float*)d_out;

  u16* W2bf = (u16*)d_ws;                              // 512 KB (fragment-major)
  float* r  = (float*)((char*)d_ws + 512 * 1024);      // 64 KB
  float* u  = r + 32 * 512;                            // 2 KB
  float* part = u + 512;                               // 8 * 65536 * 4 = 2 MB

  hipLaunchKernelGGL(prep_kernel, dim3(256), dim3(256), 0, stream,
                     hidden, W_attn, b_attn, W_cov, W2bf, r, u);
  hipLaunchKernelGGL(gemm_score, dim3(1024), dim3(512), 0, stream,
                     enc, W2bf, r, u, vv, cov, part);
  hipLaunchKernelGGL(softmax_kernel, dim3(32), dim3(256), 0, stream,
                     part, cov, out);
}